// Round 16
// baseline (580.459 us; speedup 1.0000x reference)
//
#include <hip/hip_runtime.h>
#include <hip/hip_bf16.h>

// Problem constants (B=2, T=S=2048, EMBED=1024, H=16, D=64, top-k=204)
#define TT 2048
#define KTOP 204
#define ROWS 16
#define SCS 2056  // u16 stride per score row (4112 B, 16B-aligned)
#define HSTR 130  // hist8 row stride in u32 (pad 2: bank = (2*row+pair)%32)

typedef float f32x4 __attribute__((ext_vector_type(4)));
typedef short short8 __attribute__((ext_vector_type(8)));
typedef unsigned short u16;
typedef unsigned int u32;
typedef u32 u32x2 __attribute__((ext_vector_type(2)));
typedef u32 u32x4 __attribute__((ext_vector_type(4)));

static __device__ __forceinline__ f32x4 mfma16(short8 a, short8 b, f32x4 c) {
  return __builtin_amdgcn_mfma_f32_16x16x32_bf16(a, b, c, 0, 0, 0);
}

static __device__ __forceinline__ u16 f2b(float f) {
  __hip_bfloat16 h = __float2bfloat16(f);
  return *reinterpret_cast<u16*>(&h);
}

// pack two floats to bf16 pair, RNE (hardware packed convert)
static __device__ __forceinline__ u32 cvt_pk_bf16(float lo, float hi) {
  u32 r;
  asm("v_cvt_pk_bf16_f32 %0, %1, %2" : "=v"(r) : "v"(lo), "v"(hi));
  return r;
}

#define GLOAD16(gp, lp) __builtin_amdgcn_global_load_lds( \
    (const __attribute__((address_space(1))) void*)(gp),  \
    (__attribute__((address_space(3))) void*)(lp), 16, 0, 0)

// wave-local LDS ordering fence (per-wave private buffers only)
#define WSYNC() do { __builtin_amdgcn_wave_barrier(); \
    asm volatile("s_waitcnt lgkmcnt(0)" ::: "memory"); \
    __builtin_amdgcn_wave_barrier(); } while (0)

// 256-bin rank: lane owns bins 4*lane..4*lane+3 (ascending), counts h0..h3.
// Finds bin holding the k-th largest (from bin 255 down); k -> residual rank.
static __device__ __forceinline__ void radix_rank(int h0, int h1c, int h2c,
                                                  int h3c, int lane, int& k,
                                                  u32& digOut) {
  int lsum = h0 + h1c + h2c + h3c;
  int ssum = lsum;  // inclusive suffix sum across lanes
#pragma unroll
  for (int off = 1; off < 64; off <<= 1) {
    int o = __shfl_down(ssum, off);
    ssum += (lane + off < 64) ? o : 0;
  }
  int above = ssum - lsum;  // count in lanes above this one
  int cg3 = above;
  int cg2 = cg3 + h3c;
  int cg1 = cg2 + h2c;
  int cg0 = cg1 + h1c;
  int idx = lane * 4;
  int dig = -1, nk = 0;
  if (cg0 < k && cg0 + h0 >= k) { dig = idx;     nk = k - cg0; }
  if (cg1 < k && cg1 + h1c >= k) { dig = idx + 1; nk = k - cg1; }
  if (cg2 < k && cg2 + h2c >= k) { dig = idx + 2; nk = k - cg2; }
  if (cg3 < k && cg3 + h3c >= k) { dig = idx + 3; nk = k - cg3; }
  unsigned long long ball = __ballot(dig >= 0);
  int src = __ffsll((long long)ball) - 1;
  dig = __shfl(dig, src);
  nk = __shfl(nk, src);
  digOut = (u32)dig;
  k = nk;
}

// ---------------- select + softmax (round-13/15 structure, verified) -------
// PH==2: stop after keyth (return sig). PH>=3: full softmax + writeback.
template <int JMAX, int PH>
static __device__ __forceinline__ u32 select_softmax(
    u16* __restrict__ sc, const u32* __restrict__ hist8,
    u32* __restrict__ h2w, float* __restrict__ rs, int w, int lane, int t0) {
  const int NI = JMAX * 4;
  int row0 = w, row1 = w + 8;
  bool sel0 = t0 + row0 + 1 > KTOP, sel1 = t0 + row1 + 1 > KTOP;  // uniform

  u32 rv0[NI], rv1[NI];
#pragma unroll
  for (int j = 0; j < JMAX; ++j) {
    u32x4 v0 = *(const u32x4*)&sc[row0 * SCS + lane * 8 + j * 512];
    u32x4 v1 = *(const u32x4*)&sc[row1 * SCS + lane * 8 + j * 512];
    rv0[j*4+0] = v0[0]; rv0[j*4+1] = v0[1]; rv0[j*4+2] = v0[2]; rv0[j*4+3] = v0[3];
    rv1[j*4+0] = v1[0]; rv1[j*4+1] = v1[1]; rv1[j*4+2] = v1[2]; rv1[j*4+3] = v1[3];
  }

  // pass-1 bins for both rows: lane owns bins 4l..4l+3 = pairs 2l, 2l+1
  u32 a0w = hist8[row0 * HSTR + lane * 2], a1w = hist8[row0 * HSTR + lane * 2 + 1];
  u32 b0w = hist8[row1 * HSTR + lane * 2], b1w = hist8[row1 * HSTR + lane * 2 + 1];

  // topbin per row (highest nonzero bin) -> softmax reference >= rowmax
  int lt0 = lane * 4 + ((a1w >> 16) ? 3 : ((a1w & 0xFFFFu) ? 2
                       : ((a0w >> 16) ? 1 : 0)));
  int lt1 = lane * 4 + ((b1w >> 16) ? 3 : ((b1w & 0xFFFFu) ? 2
                       : ((b0w >> 16) ? 1 : 0)));
  unsigned long long bl0 = __ballot((a0w | a1w) != 0);
  unsigned long long bl1 = __ballot((b0w | b1w) != 0);
  int top0 = __shfl(lt0, 63 - __builtin_clzll(bl0));
  int top1 = __shfl(lt1, 63 - __builtin_clzll(bl1));
  u32 ref0 = ((u32)top0 << 8) + 255u;
  u32 ref1 = ((u32)top1 << 8) + 255u;

  u32 keyth0 = 0, keyth1 = 0;
  int k0 = KTOP, k1 = KTOP;
  u32 d1_0 = 0, d1_1 = 0, d;
  if (sel0) {
    radix_rank((int)(a0w & 0xFFFF), (int)(a0w >> 16),
               (int)(a1w & 0xFFFF), (int)(a1w >> 16), lane, k0, d1_0);
  }
  if (sel1) {
    radix_rank((int)(b0w & 0xFFFF), (int)(b0w >> 16),
               (int)(b1w & 0xFFFF), (int)(b1w >> 16), lane, k1, d1_1);
  }

  // refine row0: histogram low byte of entries whose high byte == d1_0
  if (sel0) {
    h2w[lane] = 0; h2w[lane + 64] = 0;
    WSYNC();
#pragma unroll
    for (int i = 0; i < NI; ++i) {
      u32 p = rv0[i];
      u32 e0 = p & 0xFFFFu, e1 = p >> 16;
      if ((e0 >> 8) == d1_0)
        atomicAdd(&h2w[(e0 & 255u) >> 1], 1u << ((e0 & 1u) << 4));
      if ((e1 >> 8) == d1_0)
        atomicAdd(&h2w[(e1 & 255u) >> 1], 1u << ((e1 & 1u) << 4));
    }
    WSYNC();
    u32 w0 = h2w[lane * 2], w1 = h2w[lane * 2 + 1];
    radix_rank((int)(w0 & 0xFFFF), (int)(w0 >> 16),
               (int)(w1 & 0xFFFF), (int)(w1 >> 16), lane, k0, d);
    keyth0 = (d1_0 << 8) | d;
  }
  // refine row1 (same dedicated per-wave buffer, serial)
  if (sel1) {
    h2w[lane] = 0; h2w[lane + 64] = 0;
    WSYNC();
#pragma unroll
    for (int i = 0; i < NI; ++i) {
      u32 p = rv1[i];
      u32 e0 = p & 0xFFFFu, e1 = p >> 16;
      if ((e0 >> 8) == d1_1)
        atomicAdd(&h2w[(e0 & 255u) >> 1], 1u << ((e0 & 1u) << 4));
      if ((e1 >> 8) == d1_1)
        atomicAdd(&h2w[(e1 & 255u) >> 1], 1u << ((e1 & 1u) << 4));
    }
    WSYNC();
    u32 w0 = h2w[lane * 2], w1 = h2w[lane * 2 + 1];
    radix_rank((int)(w0 & 0xFFFF), (int)(w0 >> 16),
               (int)(w1 & 0xFFFF), (int)(w1 >> 16), lane, k1, d);
    keyth1 = (d1_1 << 8) | d;
  }

  if constexpr (PH == 2) {
    return keyth0 ^ (keyth1 << 16) ^ (u32)(k0 + k1) ^ ref0 ^ ref1;
  } else {
    // softmax both rows: p = exp2((key - ref) * c2) if key >= thr else 0
    u32 thr0 = keyth0 > 1u ? keyth0 : 1u;
    u32 thr1 = keyth1 > 1u ? keyth1 : 1u;
    const float c2 = 1.44269504f / 4096.f;
    float sum0 = 0.f, sum1 = 0.f;
#pragma unroll
    for (int i = 0; i < NI; ++i) {
      u32 p0 = rv0[i], p1 = rv1[i];
      u32 a0 = p0 & 0xFFFFu, a1 = p0 >> 16;
      u32 b0 = p1 & 0xFFFFu, b1 = p1 >> 16;
      float pa0 = (a0 >= thr0) ? exp2f((float)(int)(a0 - ref0) * c2) : 0.f;
      float pa1 = (a1 >= thr0) ? exp2f((float)(int)(a1 - ref0) * c2) : 0.f;
      float pb0 = (b0 >= thr1) ? exp2f((float)(int)(b0 - ref1) * c2) : 0.f;
      float pb1 = (b1 >= thr1) ? exp2f((float)(int)(b1 - ref1) * c2) : 0.f;
      sum0 += pa0 + pa1;
      sum1 += pb0 + pb1;
      rv0[i] = cvt_pk_bf16(pa0, pa1);
      rv1[i] = cvt_pk_bf16(pb0, pb1);
    }
#pragma unroll
    for (int off = 32; off; off >>= 1) {
      sum0 += __shfl_xor(sum0, off);
      sum1 += __shfl_xor(sum1, off);
    }
#pragma unroll
    for (int j = 0; j < JMAX; ++j) {
      *(u32x4*)&sc[row0 * SCS + lane * 8 + j * 512] =
          (u32x4){rv0[j*4+0], rv0[j*4+1], rv0[j*4+2], rv0[j*4+3]};
      *(u32x4*)&sc[row1 * SCS + lane * 8 + j * 512] =
          (u32x4){rv1[j*4+0], rv1[j*4+1], rv1[j*4+2], rv1[j*4+3]};
    }
    if (lane == 0) {
      rs[row0] = 1.f / fmaxf(sum0, 1e-30f);
      rs[row1] = 1.f / fmaxf(sum1, 1e-30f);
    }
    return __float_as_uint(sum0) ^ __float_as_uint(sum1);
  }
}

// ---------------- unified prep kernel (z = 0..5) ----------------
__global__ __launch_bounds__(256) void k_prep(
    const float* __restrict__ index, const float* __restrict__ memory,
    const float* __restrict__ Wq, const float* __restrict__ Wk,
    const float* __restrict__ Wv, const float* __restrict__ Wp,
    u16* __restrict__ xbi, u16* __restrict__ xbm, u16* __restrict__ wqt,
    u16* __restrict__ wkt, u16* __restrict__ wvt, u16* __restrict__ wpt) {
  int z = blockIdx.z;
  int i = blockIdx.x * 256 + threadIdx.x;
  if (z < 2) {
    const float* in = z ? memory : index;
    u16* out = z ? xbm : xbi;
    int i4 = i * 4;
    f32x4 v = *(const f32x4*)(in + i4);
    u16 r0 = f2b(v[0]), r1 = f2b(v[1]), r2 = f2b(v[2]), r3 = f2b(v[3]);
    out[i4] = r0; out[i4+1] = r1; out[i4+2] = r2; out[i4+3] = r3;
  } else if (z < 5) {
    const float* W = z == 2 ? Wq : (z == 3 ? Wk : Wv);
    u16* out = z == 2 ? wqt : (z == 3 ? wkt : wvt);
    int d = i & 63, e = (i >> 6) & 1023, h = i >> 16;
    out[(h * 64 + d) * 1024 + e] = f2b(W[i]);
  } else {
    int n = i & 1023, kk = i >> 10;
    wpt[n * 1024 + kk] = f2b(Wp[i]);
  }
}

// ---------------- bf16 MFMA GEMM core: 128x64 tile (MxN), BK=32 -----------
static __device__ __forceinline__ void gemm_core128(
    const u16* __restrict__ A, const u16* __restrict__ Bt, int m0, int n0,
    int tid, u16 (*lA)[4096], u16 (*lB)[2048], f32x4 (*acc)[4]) {
  const int K = 1024;
  int w = tid >> 6, lane = tid & 63;
  int lr = lane & 15, lg = lane >> 4;
  const u16* ga0 = A + (size_t)(m0 + (tid >> 2)) * K + (tid & 3) * 8;
  const u16* ga1 = A + (size_t)(m0 + 64 + (tid >> 2)) * K + (tid & 3) * 8;
  const u16* gb = Bt + (size_t)(n0 + (tid >> 2)) * K + (tid & 3) * 8;
  char* a0 = (char*)lA[0] + w * 1024;
  char* a1 = (char*)lA[1] + w * 1024;
  char* b0 = (char*)lB[0] + w * 1024;
  char* b1 = (char*)lB[1] + w * 1024;

  for (int kt = 0; kt < K; kt += 64) {
    __syncthreads();
    GLOAD16(ga0 + kt, a0);
    GLOAD16(ga1 + kt, a0 + 4096);
    GLOAD16(gb + kt, b0);
    GLOAD16(ga0 + kt + 32, a1);
    GLOAD16(ga1 + kt + 32, a1 + 4096);
    GLOAD16(gb + kt + 32, b1);
    __syncthreads();
#pragma unroll
    for (int p = 0; p < 2; ++p) {
      short8 af[2], bf[4];
#pragma unroll
      for (int mq = 0; mq < 2; ++mq)
        af[mq] = *(const short8*)&lA[p][(w * 32 + mq * 16 + lr) * 32 + lg * 8];
#pragma unroll
      for (int nq = 0; nq < 4; ++nq)
        bf[nq] = *(const short8*)&lB[p][(nq * 16 + lr) * 32 + lg * 8];
#pragma unroll
      for (int mq = 0; mq < 2; ++mq)
#pragma unroll
        for (int nq = 0; nq < 4; ++nq)
          acc[mq][nq] = mfma16(af[mq], bf[nq], acc[mq][nq]);
    }
  }
}

// z=0: qb = xbi@wqt (scaled 0.125); z=1: kbf = xbm@wkt; z=2: vtb = xbm@wvt^T
__global__ __launch_bounds__(256) void gemm_qkv(
    const u16* __restrict__ xbi, const u16* __restrict__ xbm,
    const u16* __restrict__ wqt, const u16* __restrict__ wkt,
    const u16* __restrict__ wvt, u16* __restrict__ qb,
    u16* __restrict__ kbf, u16* __restrict__ vtb) {
  __shared__ u16 lA[2][4096], lB[2][2048];  // 24 KB
  int tid = threadIdx.x, z = blockIdx.z;
  int m0 = blockIdx.y * 128, n0 = blockIdx.x * 64;
  const u16* A = z ? xbm : xbi;
  const u16* Bt = z == 0 ? wqt : (z == 1 ? wkt : wvt);
  f32x4 acc[2][4] = {};
  gemm_core128(A, Bt, m0, n0, tid, lA, lB, acc);

  int w = tid >> 6, lane = tid & 63, lr = lane & 15, lg = lane >> 4;
  float ascale = (z == 0) ? 0.125f : 1.f;
  u16* out0 = (z == 0) ? qb : kbf;
#pragma unroll
  for (int mq = 0; mq < 2; ++mq) {
    int mbase = m0 + w * 32 + mq * 16 + lg * 4;  // 4 consecutive t, same b
    int b = mbase >> 11;
#pragma unroll
    for (int nq = 0; nq < 4; ++nq) {
      int n = n0 + nq * 16 + lr;
      int h = n >> 6, dd = n & 63;
      if (z == 2) {
        u32 lo = cvt_pk_bf16(acc[mq][nq][0], acc[mq][nq][1]);
        u32 hi = cvt_pk_bf16(acc[mq][nq][2], acc[mq][nq][3]);
        *(u32x2*)&vtb[(((size_t)(b * 16 + h)) * 64 + dd) * TT + (mbase & 2047)] =
            (u32x2){lo, hi};
      } else {
#pragma unroll
        for (int jj = 0; jj < 4; ++jj) {
          int m = mbase + jj;
          int t = m & 2047;
          out0[(((size_t)(b * 16 + h)) * TT + t) * 64 + dd] =
              f2b(acc[mq][nq][jj] * ascale);
        }
      }
    }
  }
}

__global__ __launch_bounds__(256) void gemm_proj(
    const u16* __restrict__ A, const u16* __restrict__ Bt,
    float* __restrict__ outp, const float* __restrict__ bias) {
  __shared__ u16 lA[2][4096], lB[2][2048];
  int tid = threadIdx.x;
  int m0 = blockIdx.y * 128, n0 = blockIdx.x * 64;
  f32x4 acc[2][4] = {};
  gemm_core128(A, Bt, m0, n0, tid, lA, lB, acc);

  int w = tid >> 6, lane = tid & 63, lr = lane & 15, lg = lane >> 4;
#pragma unroll
  for (int mq = 0; mq < 2; ++mq) {
    int mbase = m0 + w * 32 + mq * 16 + lg * 4;
#pragma unroll
    for (int nq = 0; nq < 4; ++nq) {
      int n = n0 + nq * 16 + lr;
      float bi = bias[n];
#pragma unroll
      for (int jj = 0; jj < 4; ++jj)
        outp[(size_t)(mbase + jj) * 1024 + n] = acc[mq][nq][jj] + bi;
    }
  }
}

// ---------------- fused scores + exact top-k + softmax + PV ----------------
// PH=1: QK+hist+fill; PH=2: +select; PH=3: +softmax; PH=4: full (production).
// PH<4 write keep-alive checksums to dbg (dead xbm region); aob untouched.
template <int PH>
__global__ __launch_bounds__(512, 4) void k_attn(
    const u16* __restrict__ qb, const u16* __restrict__ kb,
    const u16* __restrict__ vtb, u16* __restrict__ aob,
    u32* __restrict__ dbg) {
  __shared__ u16 sc[ROWS * SCS];   // 65792 B: keys, then p (bf16)
  __shared__ u32 aux[3104];        // 12416 B: hist8[16][130] + h2[8][128]
  __shared__ float rs[ROWS];

  u32* hist8 = aux;          // [row 16][HSTR 130], u16-packed by bin parity
  u32* h2 = aux + 2080;      // [w 8][128] dedicated refine buffers

  int tid = threadIdx.x, w = tid >> 6, lane = tid & 63;
  int lr = lane & 15, lg = lane >> 4;
  int bid = blockIdx.x + 128 * blockIdx.y;
  int swz = (bid & 7) * 512 + (bid >> 3);
  int t0 = (swz & 127) * ROWS;
  int bh = swz >> 7;  // b*16 + h
  const u16* qh = qb + (size_t)bh * TT * 64;
  const u16* kh = kb + (size_t)bh * TT * 64;
  const u16* vh = vtb + (size_t)bh * 64 * TT;
  int SC = ((t0 + ROWS + 31) >> 5) << 5;  // cols rounded to PV k-step
  int jmax = (SC + 511) >> 9;             // 512-slot chunks per row (1..4)

  for (int i = tid; i < ROWS * HSTR; i += 512) hist8[i] = 0;

  short8 qf0 = *(const short8*)&qh[(size_t)(t0 + lr) * 64 + lg * 8];
  short8 qf1 = *(const short8*)&qh[(size_t)(t0 + lr) * 64 + 32 + lg * 8];
  __syncthreads();

  // ---- QK^T (swapped: C[s][q]) -> u16 keys + fused 8-bit hist ----
  {
    int t = t0 + lr;
    int s0 = w * 16;
    short8 kc0, kc1, kn0, kn1;
    if (s0 < SC) {
      kc0 = *(const short8*)&kh[(size_t)(s0 + lr) * 64 + lg * 8];
      kc1 = *(const short8*)&kh[(size_t)(s0 + lr) * 64 + 32 + lg * 8];
      if (s0 + 128 < SC) {
        kn0 = *(const short8*)&kh[(size_t)(s0 + 128 + lr) * 64 + lg * 8];
        kn1 = *(const short8*)&kh[(size_t)(s0 + 128 + lr) * 64 + 32 + lg * 8];
      }
    }
    for (; s0 < SC; s0 += 128) {
      f32x4 acc = {0.f, 0.f, 0.f, 0.f};
      acc = mfma16(kc0, qf0, acc);  // A = K rows (s), B = Q rows (q cols)
      acc = mfma16(kc1, qf1, acc);
      kc0 = kn0; kc1 = kn1;
      if (s0 + 256 < SC) {  // prefetch depth 2
        kn0 = *(const short8*)&kh[(size_t)(s0 + 256 + lr) * 64 + lg * 8];
        kn1 = *(const short8*)&kh[(size_t)(s0 + 256 + lr) * 64 + 32 + lg * 8];
      }
      int sbase = s0 + lg * 4;
      u32 key[4];
      if (s0 + 15 <= t0) {  // fully below diagonal: no masking needed
#pragma unroll
        for (int j = 0; j < 4; ++j) {
          float kf = fmaf(acc[j], 4096.f, 32768.f);
          key[j] = (u32)fminf(fmaxf(kf, 0.f), 65535.f);
        }
      } else {              // diagonal/above: per-element mask
#pragma unroll
        for (int j = 0; j < 4; ++j) {
          float kf = fmaf(acc[j], 4096.f, 32768.f);
          key[j] = (u32)fminf(fmaxf(kf, 0.f), 65535.f);
          if (sbase + j > t) key[j] = 0;
        }
      }
#pragma unroll
      for (int j = 0; j < 4; ++j)
        atomicAdd(&hist8[lr * HSTR + (key[j] >> 9)],
                  1u << (((key[j] >> 8) & 1u) << 4));
      *(u32x2*)&sc[lr * SCS + sbase] =
          (u32x2){key[0] | (key[1] << 16), key[2] | (key[3] << 16)};
    }
  }
  // zero-fill [SC, jmax*512) so register row-scans see key 0 there
  {
    int fillEnd = jmax << 9;
    for (int r = 0; r < ROWS; ++r)
      for (int s = SC + tid * 8; s < fillEnd; s += 512 * 8)
        *(u32x4*)&sc[r * SCS + s] = (u32x4){0, 0, 0, 0};
  }
  __syncthreads();

  if constexpr (PH == 1) {  // keep keys + hist live
    u32 v = *(const u32*)&sc[(tid & 15) * SCS + ((tid >> 4) & 127) * 16];
    dbg[(size_t)bid * 512 + tid] = v ^ hist8[tid & 2047];
    return;
  }

  u32 sig = 0;
  switch (jmax) {
    case 1: sig = select_softmax<1, PH>(sc, hist8, &h2[w * 128], rs, w, lane, t0); break;
    case 2: sig = select_softmax<2, PH>(sc, hist8, &h2[w * 128], rs, w, lane, t0); break;
    case 3: sig = select_softmax<3, PH>(sc, hist8, &h2[w * 128], rs, w, lane, t0); break;
    default: sig = select_softmax<4, PH>(sc, hist8, &h2[w * 128], rs, w, lane, t0); break;
  }
  if constexpr (PH == 2) {
    dbg[(size_t)bid * 512 + tid] = sig;
    return;
  }
  __syncthreads();
  if constexpr (PH == 3) {  // keep p + rs live
    u32 v = *(const u32*)&sc[(tid & 15) * SCS + ((tid >> 4) & 127) * 16];
    dbg[(size_t)bid * 512 + tid] = v ^ sig ^ __float_as_uint(rs[tid & 15]);
    return;
  }

  // ---- PV: O[t][d] = sum_s P[t][s] V[s][d]; 4 d-groups x 2 k-halves ----
  float* po = (float*)aux;  // [2][16][68] f32 partials (hists dead now)
  int d0 = (w & 3) * 16;
  int h = w >> 2;
  int tiles = SC >> 5;
  int mid = ((tiles + 1) >> 1) << 5;
  int kb0 = h ? mid : 0;
  int kb1 = h ? SC : mid;
  f32x4 o = {0.f, 0.f, 0.f, 0.f};
  {
    int kk = kb0;
    short8 bn;
    if (kk < kb1)
      bn = *(const short8*)&vh[(size_t)(d0 + lr) * TT + kk + lg * 8];
    for (; kk < kb1; kk += 32) {
      short8 b = bn;
      int kn = kk + 32;
      if (kn < kb1)  // prefetch next V fragment
        bn = *(const short8*)&vh[(size_t)(d0 + lr) * TT + kn + lg * 8];
      short8 a = *(const short8*)&sc[lr * SCS + kk + lg * 8];
      o = mfma16(a, b, o);
    }
  }
#pragma unroll
  for (int j = 0; j < 4; ++j)
    po[(h * ROWS + lg * 4 + j) * 68 + d0 + lr] = o[j];
  __syncthreads();

  if (w < 4) {
    int b_ = bh >> 4, h_ = bh & 15;
    int dd0 = w * 16;
#pragma unroll
    for (int j = 0; j < 4; ++j) {
      int row = lg * 4 + j;
      float val = (po[row * 68 + dd0 + lr] + po[(ROWS + row) * 68 + dd0 + lr]) *
                  rs[row];
      aob[((size_t)(b_ * TT + t0 + row)) * 1024 + h_ * 64 + dd0 + lr] = f2b(val);
    }
  }
}

// ---------------- launch ----------------

extern "C" void kernel_launch(void* const* d_in, const int* in_sizes, int n_in,
                              void* d_out, int out_size, void* d_ws, size_t ws_size,
                              hipStream_t stream) {
  const float* index  = (const float*)d_in[0];
  const float* memory = (const float*)d_in[1];
  const float* Wq     = (const float*)d_in[2];
  const float* Wk     = (const float*)d_in[3];
  const float* Wv     = (const float*)d_in[4];
  const float* Wp     = (const float*)d_in[5];
  const float* bp     = (const float*)d_in[6];

  char* ws = (char*)d_ws;
  const size_t MB = 1024 * 1024;
  u16* xbi = (u16*)(ws + 0);
  u16* xbm = (u16*)(ws + 8 * MB);
  u16* wqt = (u16*)(ws + 16 * MB);
  u16* wkt = (u16*)(ws + 18 * MB);
  u16* wvt = (u16*)(ws + 20 * MB);
  u16* wpt = (u16*)(ws + 22 * MB);
  u16* qb  = (u16*)(ws + 24 * MB);
  u16* kbf = (u16*)(ws + 32 * MB);
  u16* vtb = (u16*)(ws + 40 * MB);
  u16* aob = xbi;        // reuse (xbi dead after gemm_qkv)
  u32* dbg = (u32*)xbm;  // reuse (xbm dead after gemm_qkv); 8 MB fits

  k_prep<<<dim3(4096, 1, 6), 256, 0, stream>>>(index, memory, Wq, Wk, Wv, Wp,
                                               xbi, xbm, wqt, wkt, wvt, wpt);

  // q pre-scaled by HEAD^-0.5 = 0.125 so QK^T yields final scores
  gemm_qkv<<<dim3(16, 32, 3), 256, 0, stream>>>(xbi, xbm, wqt, wkt, wvt,
                                                qb, kbf, vtb);

  // production attention first (path identical to round 15)
  k_attn<4><<<dim3(128, 32), 512, 0, stream>>>(qb, kbf, vtb, aob, dbg);

  // phase-ablation probes, full grid (land in rocprof top-5)
  k_attn<1><<<dim3(128, 32), 512, 0, stream>>>(qb, kbf, vtb, aob, dbg);
  k_attn<2><<<dim3(128, 32), 512, 0, stream>>>(qb, kbf, vtb, aob, dbg);
  k_attn<3><<<dim3(128, 32), 512, 0, stream>>>(qb, kbf, vtb, aob, dbg);

  gemm_proj<<<dim3(16, 32), 256, 0, stream>>>(aob, wpt, (float*)d_out, bp);
}

// Round 17
// 262.234 us; speedup vs baseline: 2.2135x; 2.2135x over previous
//
#include <hip/hip_runtime.h>
#include <hip/hip_bf16.h>

// Problem constants (B=2, T=S=2048, EMBED=1024, H=16, D=64, top-k=204)
#define TT 2048
#define KTOP 204
#define ROWS 16
#define SCS 2056  // u16 stride per score row (4112 B, 16B-aligned)
#define HSTR 130  // hist8 row stride in u32 (pad 2: bank = (2*row+pair)%32)

typedef float f32x4 __attribute__((ext_vector_type(4)));
typedef short short8 __attribute__((ext_vector_type(8)));
typedef unsigned short u16;
typedef unsigned int u32;
typedef u32 u32x2 __attribute__((ext_vector_type(2)));
typedef u32 u32x4 __attribute__((ext_vector_type(4)));

static __device__ __forceinline__ f32x4 mfma16(short8 a, short8 b, f32x4 c) {
  return __builtin_amdgcn_mfma_f32_16x16x32_bf16(a, b, c, 0, 0, 0);
}

static __device__ __forceinline__ u16 f2b(float f) {
  __hip_bfloat16 h = __float2bfloat16(f);
  return *reinterpret_cast<u16*>(&h);
}

// pack two floats to bf16 pair, RNE (hardware packed convert)
static __device__ __forceinline__ u32 cvt_pk_bf16(float lo, float hi) {
  u32 r;
  asm("v_cvt_pk_bf16_f32 %0, %1, %2" : "=v"(r) : "v"(lo), "v"(hi));
  return r;
}

#define GLOAD16(gp, lp) __builtin_amdgcn_global_load_lds( \
    (const __attribute__((address_space(1))) void*)(gp),  \
    (__attribute__((address_space(3))) void*)(lp), 16, 0, 0)

// wave-local LDS ordering fence (per-wave private buffers only)
#define WSYNC() do { __builtin_amdgcn_wave_barrier(); \
    asm volatile("s_waitcnt lgkmcnt(0)" ::: "memory"); \
    __builtin_amdgcn_wave_barrier(); } while (0)

// 256-bin rank: lane owns bins 4*lane..4*lane+3 (ascending), counts h0..h3.
// Finds bin holding the k-th largest (from bin 255 down); k -> residual rank.
static __device__ __forceinline__ void radix_rank(int h0, int h1c, int h2c,
                                                  int h3c, int lane, int& k,
                                                  u32& digOut) {
  int lsum = h0 + h1c + h2c + h3c;
  int ssum = lsum;  // inclusive suffix sum across lanes
#pragma unroll
  for (int off = 1; off < 64; off <<= 1) {
    int o = __shfl_down(ssum, off);
    ssum += (lane + off < 64) ? o : 0;
  }
  int above = ssum - lsum;  // count in lanes above this one
  int cg3 = above;
  int cg2 = cg3 + h3c;
  int cg1 = cg2 + h2c;
  int cg0 = cg1 + h1c;
  int idx = lane * 4;
  int dig = -1, nk = 0;
  if (cg0 < k && cg0 + h0 >= k) { dig = idx;     nk = k - cg0; }
  if (cg1 < k && cg1 + h1c >= k) { dig = idx + 1; nk = k - cg1; }
  if (cg2 < k && cg2 + h2c >= k) { dig = idx + 2; nk = k - cg2; }
  if (cg3 < k && cg3 + h3c >= k) { dig = idx + 3; nk = k - cg3; }
  unsigned long long ball = __ballot(dig >= 0);
  int src = __ffsll((long long)ball) - 1;
  dig = __shfl(dig, src);
  nk = __shfl(nk, src);
  digOut = (u32)dig;
  k = nk;
}

// ---------------- select + softmax (round-13/15 structure, verified) -------
template <int JMAX>
static __device__ __forceinline__ void select_softmax(
    u16* __restrict__ sc, const u32* __restrict__ hist8,
    u32* __restrict__ h2w, float* __restrict__ rs, int w, int lane, int t0) {
  const int NI = JMAX * 4;
  int row0 = w, row1 = w + 8;
  bool sel0 = t0 + row0 + 1 > KTOP, sel1 = t0 + row1 + 1 > KTOP;  // uniform

  u32 rv0[NI], rv1[NI];
#pragma unroll
  for (int j = 0; j < JMAX; ++j) {
    u32x4 v0 = *(const u32x4*)&sc[row0 * SCS + lane * 8 + j * 512];
    u32x4 v1 = *(const u32x4*)&sc[row1 * SCS + lane * 8 + j * 512];
    rv0[j*4+0] = v0[0]; rv0[j*4+1] = v0[1]; rv0[j*4+2] = v0[2]; rv0[j*4+3] = v0[3];
    rv1[j*4+0] = v1[0]; rv1[j*4+1] = v1[1]; rv1[j*4+2] = v1[2]; rv1[j*4+3] = v1[3];
  }

  // pass-1 bins for both rows: lane owns bins 4l..4l+3 = pairs 2l, 2l+1
  u32 a0w = hist8[row0 * HSTR + lane * 2], a1w = hist8[row0 * HSTR + lane * 2 + 1];
  u32 b0w = hist8[row1 * HSTR + lane * 2], b1w = hist8[row1 * HSTR + lane * 2 + 1];

  // topbin per row (highest nonzero bin) -> softmax reference >= rowmax
  int lt0 = lane * 4 + ((a1w >> 16) ? 3 : ((a1w & 0xFFFFu) ? 2
                       : ((a0w >> 16) ? 1 : 0)));
  int lt1 = lane * 4 + ((b1w >> 16) ? 3 : ((b1w & 0xFFFFu) ? 2
                       : ((b0w >> 16) ? 1 : 0)));
  unsigned long long bl0 = __ballot((a0w | a1w) != 0);
  unsigned long long bl1 = __ballot((b0w | b1w) != 0);
  int top0 = __shfl(lt0, 63 - __builtin_clzll(bl0));
  int top1 = __shfl(lt1, 63 - __builtin_clzll(bl1));
  u32 ref0 = ((u32)top0 << 8) + 255u;
  u32 ref1 = ((u32)top1 << 8) + 255u;

  u32 keyth0 = 0, keyth1 = 0;
  int k0 = KTOP, k1 = KTOP;
  u32 d1_0 = 0, d1_1 = 0, d;
  if (sel0) {
    radix_rank((int)(a0w & 0xFFFF), (int)(a0w >> 16),
               (int)(a1w & 0xFFFF), (int)(a1w >> 16), lane, k0, d1_0);
  }
  if (sel1) {
    radix_rank((int)(b0w & 0xFFFF), (int)(b0w >> 16),
               (int)(b1w & 0xFFFF), (int)(b1w >> 16), lane, k1, d1_1);
  }

  // refine row0: histogram low byte of entries whose high byte == d1_0
  if (sel0) {
    h2w[lane] = 0; h2w[lane + 64] = 0;
    WSYNC();
#pragma unroll
    for (int i = 0; i < NI; ++i) {
      u32 p = rv0[i];
      u32 e0 = p & 0xFFFFu, e1 = p >> 16;
      if ((e0 >> 8) == d1_0)
        atomicAdd(&h2w[(e0 & 255u) >> 1], 1u << ((e0 & 1u) << 4));
      if ((e1 >> 8) == d1_0)
        atomicAdd(&h2w[(e1 & 255u) >> 1], 1u << ((e1 & 1u) << 4));
    }
    WSYNC();
    u32 w0 = h2w[lane * 2], w1 = h2w[lane * 2 + 1];
    radix_rank((int)(w0 & 0xFFFF), (int)(w0 >> 16),
               (int)(w1 & 0xFFFF), (int)(w1 >> 16), lane, k0, d);
    keyth0 = (d1_0 << 8) | d;
  }
  // refine row1 (same dedicated per-wave buffer, serial)
  if (sel1) {
    h2w[lane] = 0; h2w[lane + 64] = 0;
    WSYNC();
#pragma unroll
    for (int i = 0; i < NI; ++i) {
      u32 p = rv1[i];
      u32 e0 = p & 0xFFFFu, e1 = p >> 16;
      if ((e0 >> 8) == d1_1)
        atomicAdd(&h2w[(e0 & 255u) >> 1], 1u << ((e0 & 1u) << 4));
      if ((e1 >> 8) == d1_1)
        atomicAdd(&h2w[(e1 & 255u) >> 1], 1u << ((e1 & 1u) << 4));
    }
    WSYNC();
    u32 w0 = h2w[lane * 2], w1 = h2w[lane * 2 + 1];
    radix_rank((int)(w0 & 0xFFFF), (int)(w0 >> 16),
               (int)(w1 & 0xFFFF), (int)(w1 >> 16), lane, k1, d);
    keyth1 = (d1_1 << 8) | d;
  }

  // softmax both rows: p = exp2((key - ref) * c2) if key >= thr else 0
  u32 thr0 = keyth0 > 1u ? keyth0 : 1u;
  u32 thr1 = keyth1 > 1u ? keyth1 : 1u;
  const float c2 = 1.44269504f / 4096.f;
  float sum0 = 0.f, sum1 = 0.f;
#pragma unroll
  for (int i = 0; i < NI; ++i) {
    u32 p0 = rv0[i], p1 = rv1[i];
    u32 a0 = p0 & 0xFFFFu, a1 = p0 >> 16;
    u32 b0 = p1 & 0xFFFFu, b1 = p1 >> 16;
    float pa0 = (a0 >= thr0) ? exp2f((float)(int)(a0 - ref0) * c2) : 0.f;
    float pa1 = (a1 >= thr0) ? exp2f((float)(int)(a1 - ref0) * c2) : 0.f;
    float pb0 = (b0 >= thr1) ? exp2f((float)(int)(b0 - ref1) * c2) : 0.f;
    float pb1 = (b1 >= thr1) ? exp2f((float)(int)(b1 - ref1) * c2) : 0.f;
    sum0 += pa0 + pa1;
    sum1 += pb0 + pb1;
    rv0[i] = cvt_pk_bf16(pa0, pa1);
    rv1[i] = cvt_pk_bf16(pb0, pb1);
  }
#pragma unroll
  for (int off = 32; off; off >>= 1) {
    sum0 += __shfl_xor(sum0, off);
    sum1 += __shfl_xor(sum1, off);
  }
#pragma unroll
  for (int j = 0; j < JMAX; ++j) {
    *(u32x4*)&sc[row0 * SCS + lane * 8 + j * 512] =
        (u32x4){rv0[j*4+0], rv0[j*4+1], rv0[j*4+2], rv0[j*4+3]};
    *(u32x4*)&sc[row1 * SCS + lane * 8 + j * 512] =
        (u32x4){rv1[j*4+0], rv1[j*4+1], rv1[j*4+2], rv1[j*4+3]};
  }
  if (lane == 0) {
    rs[row0] = 1.f / fmaxf(sum0, 1e-30f);
    rs[row1] = 1.f / fmaxf(sum1, 1e-30f);
  }
}

// ---------------- unified prep kernel (z = 0..5) ----------------
__global__ __launch_bounds__(256) void k_prep(
    const float* __restrict__ index, const float* __restrict__ memory,
    const float* __restrict__ Wq, const float* __restrict__ Wk,
    const float* __restrict__ Wv, const float* __restrict__ Wp,
    u16* __restrict__ xbi, u16* __restrict__ xbm, u16* __restrict__ wqt,
    u16* __restrict__ wkt, u16* __restrict__ wvt, u16* __restrict__ wpt) {
  int z = blockIdx.z;
  int i = blockIdx.x * 256 + threadIdx.x;
  if (z < 2) {
    const float* in = z ? memory : index;
    u16* out = z ? xbm : xbi;
    int i4 = i * 4;
    f32x4 v = *(const f32x4*)(in + i4);
    u16 r0 = f2b(v[0]), r1 = f2b(v[1]), r2 = f2b(v[2]), r3 = f2b(v[3]);
    out[i4] = r0; out[i4+1] = r1; out[i4+2] = r2; out[i4+3] = r3;
  } else if (z < 5) {
    const float* W = z == 2 ? Wq : (z == 3 ? Wk : Wv);
    u16* out = z == 2 ? wqt : (z == 3 ? wkt : wvt);
    int d = i & 63, e = (i >> 6) & 1023, h = i >> 16;
    out[(h * 64 + d) * 1024 + e] = f2b(W[i]);
  } else {
    int n = i & 1023, kk = i >> 10;
    wpt[n * 1024 + kk] = f2b(Wp[i]);
  }
}

// ---------------- bf16 MFMA GEMM core: 128x64 tile (MxN), BK=32 -----------
static __device__ __forceinline__ void gemm_core128(
    const u16* __restrict__ A, const u16* __restrict__ Bt, int m0, int n0,
    int tid, u16 (*lA)[4096], u16 (*lB)[2048], f32x4 (*acc)[4]) {
  const int K = 1024;
  int w = tid >> 6, lane = tid & 63;
  int lr = lane & 15, lg = lane >> 4;
  const u16* ga0 = A + (size_t)(m0 + (tid >> 2)) * K + (tid & 3) * 8;
  const u16* ga1 = A + (size_t)(m0 + 64 + (tid >> 2)) * K + (tid & 3) * 8;
  const u16* gb = Bt + (size_t)(n0 + (tid >> 2)) * K + (tid & 3) * 8;
  char* a0 = (char*)lA[0] + w * 1024;
  char* a1 = (char*)lA[1] + w * 1024;
  char* b0 = (char*)lB[0] + w * 1024;
  char* b1 = (char*)lB[1] + w * 1024;

  for (int kt = 0; kt < K; kt += 64) {
    __syncthreads();
    GLOAD16(ga0 + kt, a0);
    GLOAD16(ga1 + kt, a0 + 4096);
    GLOAD16(gb + kt, b0);
    GLOAD16(ga0 + kt + 32, a1);
    GLOAD16(ga1 + kt + 32, a1 + 4096);
    GLOAD16(gb + kt + 32, b1);
    __syncthreads();
    __builtin_amdgcn_s_setprio(1);
#pragma unroll
    for (int p = 0; p < 2; ++p) {
      short8 af[2], bf[4];
#pragma unroll
      for (int mq = 0; mq < 2; ++mq)
        af[mq] = *(const short8*)&lA[p][(w * 32 + mq * 16 + lr) * 32 + lg * 8];
#pragma unroll
      for (int nq = 0; nq < 4; ++nq)
        bf[nq] = *(const short8*)&lB[p][(nq * 16 + lr) * 32 + lg * 8];
#pragma unroll
      for (int mq = 0; mq < 2; ++mq)
#pragma unroll
        for (int nq = 0; nq < 4; ++nq)
          acc[mq][nq] = mfma16(af[mq], bf[nq], acc[mq][nq]);
    }
    __builtin_amdgcn_s_setprio(0);
  }
}

// z=0: qb = xbi@wqt (scaled 0.125); z=1: kbf = xbm@wkt; z=2: vtb = xbm@wvt^T
__global__ __launch_bounds__(256) void gemm_qkv(
    const u16* __restrict__ xbi, const u16* __restrict__ xbm,
    const u16* __restrict__ wqt, const u16* __restrict__ wkt,
    const u16* __restrict__ wvt, u16* __restrict__ qb,
    u16* __restrict__ kbf, u16* __restrict__ vtb) {
  __shared__ u16 lA[2][4096], lB[2][2048];  // 24 KB
  int tid = threadIdx.x, z = blockIdx.z;
  int m0 = blockIdx.y * 128, n0 = blockIdx.x * 64;
  const u16* A = z ? xbm : xbi;
  const u16* Bt = z == 0 ? wqt : (z == 1 ? wkt : wvt);
  f32x4 acc[2][4] = {};
  gemm_core128(A, Bt, m0, n0, tid, lA, lB, acc);

  int w = tid >> 6, lane = tid & 63, lr = lane & 15, lg = lane >> 4;
  float ascale = (z == 0) ? 0.125f : 1.f;
  u16* out0 = (z == 0) ? qb : kbf;
#pragma unroll
  for (int mq = 0; mq < 2; ++mq) {
    int mbase = m0 + w * 32 + mq * 16 + lg * 4;  // 4 consecutive t, same b
    int b = mbase >> 11;
#pragma unroll
    for (int nq = 0; nq < 4; ++nq) {
      int n = n0 + nq * 16 + lr;
      int h = n >> 6, dd = n & 63;
      if (z == 2) {
        u32 lo = cvt_pk_bf16(acc[mq][nq][0], acc[mq][nq][1]);
        u32 hi = cvt_pk_bf16(acc[mq][nq][2], acc[mq][nq][3]);
        *(u32x2*)&vtb[(((size_t)(b * 16 + h)) * 64 + dd) * TT + (mbase & 2047)] =
            (u32x2){lo, hi};
      } else {
#pragma unroll
        for (int jj = 0; jj < 4; ++jj) {
          int m = mbase + jj;
          int t = m & 2047;
          out0[(((size_t)(b * 16 + h)) * TT + t) * 64 + dd] =
              f2b(acc[mq][nq][jj] * ascale);
        }
      }
    }
  }
}

__global__ __launch_bounds__(256) void gemm_proj(
    const u16* __restrict__ A, const u16* __restrict__ Bt,
    float* __restrict__ outp, const float* __restrict__ bias) {
  __shared__ u16 lA[2][4096], lB[2][2048];
  int tid = threadIdx.x;
  int m0 = blockIdx.y * 128, n0 = blockIdx.x * 64;
  f32x4 acc[2][4] = {};
  gemm_core128(A, Bt, m0, n0, tid, lA, lB, acc);

  int w = tid >> 6, lane = tid & 63, lr = lane & 15, lg = lane >> 4;
#pragma unroll
  for (int mq = 0; mq < 2; ++mq) {
    int mbase = m0 + w * 32 + mq * 16 + lg * 4;
#pragma unroll
    for (int nq = 0; nq < 4; ++nq) {
      int n = n0 + nq * 16 + lr;
      float bi = bias[n];
#pragma unroll
      for (int jj = 0; jj < 4; ++jj)
        outp[(size_t)(mbase + jj) * 1024 + n] = acc[mq][nq][jj] + bi;
    }
  }
}

// ---------------- fused scores + exact top-k + softmax + PV ----------------
// Round-15 production structure + s_setprio(1) around MFMA clusters (T5:
// 2 blocks/CU at different phases -> scheduler favors MFMA-entering waves).
__global__ __launch_bounds__(512, 4) void k_attn(
    const u16* __restrict__ qb, const u16* __restrict__ kb,
    const u16* __restrict__ vtb, u16* __restrict__ aob) {
  __shared__ u16 sc[ROWS * SCS];   // 65792 B: keys, then p (bf16)
  __shared__ u32 aux[3104];        // 12416 B: hist8[16][130] + h2[8][128];
                                   // reused as f32 po[2][16][68] for PV
  __shared__ float rs[ROWS];
  // total LDS = 78272 B -> 2 blocks/CU

  u32* hist8 = aux;          // [row 16][HSTR 130], u16-packed by bin parity
  u32* h2 = aux + 2080;      // [w 8][128] dedicated refine buffers

  int tid = threadIdx.x, w = tid >> 6, lane = tid & 63;
  int lr = lane & 15, lg = lane >> 4;
  // XCD swizzle: grid (128, 32) -> flat 4096; XCD k (bid%8) gets contiguous
  // chunk = heads 4k..4k+3, all t0. Bijective (4096 % 8 == 0).
  int bid = blockIdx.x + 128 * blockIdx.y;
  int swz = (bid & 7) * 512 + (bid >> 3);
  int t0 = (swz & 127) * ROWS;
  int bh = swz >> 7;  // b*16 + h
  const u16* qh = qb + (size_t)bh * TT * 64;
  const u16* kh = kb + (size_t)bh * TT * 64;
  const u16* vh = vtb + (size_t)bh * 64 * TT;
  int SC = ((t0 + ROWS + 31) >> 5) << 5;  // cols rounded to PV k-step
  int jmax = (SC + 511) >> 9;             // 512-slot chunks per row (1..4)

  for (int i = tid; i < ROWS * HSTR; i += 512) hist8[i] = 0;

  // Q fragments (B operand: col=q-row=lr, k=lg*8..). q pre-scaled by 1/8.
  short8 qf0 = *(const short8*)&qh[(size_t)(t0 + lr) * 64 + lg * 8];
  short8 qf1 = *(const short8*)&qh[(size_t)(t0 + lr) * 64 + 32 + lg * 8];
  __syncthreads();

  // ---- QK^T (swapped: C[s][q]) -> u16 keys + fused 8-bit hist ----
  {
    int t = t0 + lr;
    int s0 = w * 16;
    short8 kc0, kc1, kn0, kn1;
    if (s0 < SC) {
      kc0 = *(const short8*)&kh[(size_t)(s0 + lr) * 64 + lg * 8];
      kc1 = *(const short8*)&kh[(size_t)(s0 + lr) * 64 + 32 + lg * 8];
      if (s0 + 128 < SC) {
        kn0 = *(const short8*)&kh[(size_t)(s0 + 128 + lr) * 64 + lg * 8];
        kn1 = *(const short8*)&kh[(size_t)(s0 + 128 + lr) * 64 + 32 + lg * 8];
      }
    }
    for (; s0 < SC; s0 += 128) {
      __builtin_amdgcn_s_setprio(1);
      f32x4 acc = {0.f, 0.f, 0.f, 0.f};
      acc = mfma16(kc0, qf0, acc);  // A = K rows (s), B = Q rows (q cols)
      acc = mfma16(kc1, qf1, acc);
      __builtin_amdgcn_s_setprio(0);
      kc0 = kn0; kc1 = kn1;
      if (s0 + 256 < SC) {  // prefetch depth 2
        kn0 = *(const short8*)&kh[(size_t)(s0 + 256 + lr) * 64 + lg * 8];
        kn1 = *(const short8*)&kh[(size_t)(s0 + 256 + lr) * 64 + 32 + lg * 8];
      }
      int sbase = s0 + lg * 4;
      u32 key[4];
      if (s0 + 15 <= t0) {  // fully below diagonal: no masking needed
#pragma unroll
        for (int j = 0; j < 4; ++j) {
          float kf = fmaf(acc[j], 4096.f, 32768.f);
          key[j] = (u32)fminf(fmaxf(kf, 0.f), 65535.f);
        }
      } else {              // diagonal/above: per-element mask
#pragma unroll
        for (int j = 0; j < 4; ++j) {
          float kf = fmaf(acc[j], 4096.f, 32768.f);
          key[j] = (u32)fminf(fmaxf(kf, 0.f), 65535.f);
          if (sbase + j > t) key[j] = 0;
        }
      }
#pragma unroll
      for (int j = 0; j < 4; ++j)
        atomicAdd(&hist8[lr * HSTR + (key[j] >> 9)],
                  1u << (((key[j] >> 8) & 1u) << 4));
      *(u32x2*)&sc[lr * SCS + sbase] =
          (u32x2){key[0] | (key[1] << 16), key[2] | (key[3] << 16)};
    }
  }
  // zero-fill [SC, jmax*512) so register row-scans see key 0 there
  {
    int fillEnd = jmax << 9;
    for (int r = 0; r < ROWS; ++r)
      for (int s = SC + tid * 8; s < fillEnd; s += 512 * 8)
        *(u32x4*)&sc[r * SCS + s] = (u32x4){0, 0, 0, 0};
  }
  __syncthreads();

  // ---- select + softmax, trip counts bound by jmax (block-uniform) ----
  switch (jmax) {
    case 1: select_softmax<1>(sc, hist8, &h2[w * 128], rs, w, lane, t0); break;
    case 2: select_softmax<2>(sc, hist8, &h2[w * 128], rs, w, lane, t0); break;
    case 3: select_softmax<3>(sc, hist8, &h2[w * 128], rs, w, lane, t0); break;
    default: select_softmax<4>(sc, hist8, &h2[w * 128], rs, w, lane, t0); break;
  }
  __syncthreads();

  // ---- PV: O[t][d] = sum_s P[t][s] V[s][d]; 4 d-groups x 2 k-halves ----
  float* po = (float*)aux;  // [2][16][68] f32 partials (hists dead now)
  int d0 = (w & 3) * 16;
  int h = w >> 2;
  int tiles = SC >> 5;
  int mid = ((tiles + 1) >> 1) << 5;
  int kb0 = h ? mid : 0;
  int kb1 = h ? SC : mid;
  f32x4 o = {0.f, 0.f, 0.f, 0.f};
  {
    int kk = kb0;
    short8 bn;
    if (kk < kb1)
      bn = *(const short8*)&vh[(size_t)(d0 + lr) * TT + kk + lg * 8];
    __builtin_amdgcn_s_setprio(1);
    for (; kk < kb1; kk += 32) {
      short8 b = bn;
      int kn = kk + 32;
      if (kn < kb1)  // prefetch next V fragment
        bn = *(const short8*)&vh[(size_t)(d0 + lr) * TT + kn + lg * 8];
      short8 a = *(const short8*)&sc[lr * SCS + kk + lg * 8];
      o = mfma16(a, b, o);
    }
    __builtin_amdgcn_s_setprio(0);
  }
#pragma unroll
  for (int j = 0; j < 4; ++j)
    po[(h * ROWS + lg * 4 + j) * 68 + d0 + lr] = o[j];
  __syncthreads();

  if (w < 4) {
    int b_ = bh >> 4, h_ = bh & 15;
    int dd0 = w * 16;
#pragma unroll
    for (int j = 0; j < 4; ++j) {
      int row = lg * 4 + j;
      float val = (po[row * 68 + dd0 + lr] + po[(ROWS + row) * 68 + dd0 + lr]) *
                  rs[row];
      aob[((size_t)(b_ * TT + t0 + row)) * 1024 + h_ * 64 + dd0 + lr] = f2b(val);
    }
  }
}

// ---------------- launch ----------------

extern "C" void kernel_launch(void* const* d_in, const int* in_sizes, int n_in,
                              void* d_out, int out_size, void* d_ws, size_t ws_size,
                              hipStream_t stream) {
  const float* index  = (const float*)d_in[0];
  const float* memory = (const float*)d_in[1];
  const float* Wq     = (const float*)d_in[2];
  const float* Wk     = (const float*)d_in[3];
  const float* Wv     = (const float*)d_in[4];
  const float* Wp     = (const float*)d_in[5];
  const float* bp     = (const float*)d_in[6];

  char* ws = (char*)d_ws;
  const size_t MB = 1024 * 1024;
  u16* xbi = (u16*)(ws + 0);
  u16* xbm = (u16*)(ws + 8 * MB);
  u16* wqt = (u16*)(ws + 16 * MB);
  u16* wkt = (u16*)(ws + 18 * MB);
  u16* wvt = (u16*)(ws + 20 * MB);
  u16* wpt = (u16*)(ws + 22 * MB);
  u16* qb  = (u16*)(ws + 24 * MB);
  u16* kbf = (u16*)(ws + 32 * MB);
  u16* vtb = (u16*)(ws + 40 * MB);
  u16* aob = xbi;  // reuse (xbi dead after gemm_qkv)

  k_prep<<<dim3(4096, 1, 6), 256, 0, stream>>>(index, memory, Wq, Wk, Wv, Wp,
                                               xbi, xbm, wqt, wkt, wvt, wpt);

  // q pre-scaled by HEAD^-0.5 = 0.125 so QK^T yields final scores
  gemm_qkv<<<dim3(16, 32, 3), 256, 0, stream>>>(xbi, xbm, wqt, wkt, wvt,
                                                qb, kbf, vtb);

  k_attn<<<dim3(128, 32), 512, 0, stream>>>(qb, kbf, vtb, aob);

  gemm_proj<<<dim3(16, 32), 256, 0, stream>>>(aob, wpt, (float*)d_out, bp);
}